// Round 3
// baseline (188.026 us; speedup 1.0000x reference)
//
#include <hip/hip_runtime.h>
#include <hip/hip_bf16.h>
#include <cstdint>

// ---------------- problem constants ----------------
#define BB 1024          // batch
#define DD 512           // dim
#define CC 50000         // classes
#define SCALE_F 64.0f
#define COS_M_F 0.87758256189037276f
#define SIN_M_F 0.47942553860420301f
#define TH_F   (-0.87758256189037276f)
#define MM_F   0.23971276930210156f

// 8-phase path geometry: BM=256, BN=256, BK=64
#define NTN 196          // ceil(50000/256) n-tiles
#define PSTRIDE 784      // partials per row = NTN*4 waves
#define NBLK8 784        // 196*4 m-tiles = 8*98 (exact XCD divisibility)
// fallback geometry (round-2 proven): BN=64
#define NTFB 782
#define NBLKFB 3128

typedef __attribute__((ext_vector_type(8))) short short8;
typedef __attribute__((ext_vector_type(8))) unsigned short ushort8;
typedef __attribute__((ext_vector_type(4))) float f32x4;

__device__ __forceinline__ unsigned short f2bf(float x) {
    union { __hip_bfloat16 h; unsigned short u; } v;
    v.h = __float2bfloat16(x);
    return v.u;
}

// ---------------- ws layout (bytes) ----------------
#define OFF_PM   ((size_t)0)                          // [1024][784] float
#define OFF_PS   (OFF_PM + (size_t)BB*PSTRIDE*4)      // [1024][784] float
#define OFF_LAB  (OFF_PS + (size_t)BB*PSTRIDE*4)      // [1024] float
#define OFF_NLL  (OFF_LAB + 4096)                     // [1024] float
#define OFF_E    (OFF_NLL + 4096)                     // [1024][512] bf16
#define OFF_WBF  (OFF_E + (size_t)BB*DD*2)            // [50000][512] bf16 normalized
#define NEED_PRE (OFF_WBF + (size_t)CC*DD*2)
#define OFF_INV  OFF_WBF                              // fallback: [50000] float
#define NEED_FB  (OFF_INV + 204800)

// ---------------- kernel 1: normalize embeddings -> bf16 ----------------
__global__ void norm_e_kernel(const float* __restrict__ e, unsigned short* __restrict__ ebf) {
    const int b = blockIdx.x;          // 1024 blocks
    const int l = threadIdx.x;         // 64 threads
    const float4* row = reinterpret_cast<const float4*>(e + (size_t)b * DD);
    float4 v0 = row[l * 2 + 0];
    float4 v1 = row[l * 2 + 1];
    float s = v0.x*v0.x + v0.y*v0.y + v0.z*v0.z + v0.w*v0.w
            + v1.x*v1.x + v1.y*v1.y + v1.z*v1.z + v1.w*v1.w;
    #pragma unroll
    for (int m = 1; m < 64; m <<= 1) s += __shfl_xor(s, m);
    float inv = 1.0f / fmaxf(sqrtf(s), 1e-12f);
    ushort8 h;
    h[0]=f2bf(v0.x*inv); h[1]=f2bf(v0.y*inv); h[2]=f2bf(v0.z*inv); h[3]=f2bf(v0.w*inv);
    h[4]=f2bf(v1.x*inv); h[5]=f2bf(v1.y*inv); h[6]=f2bf(v1.z*inv); h[7]=f2bf(v1.w*inv);
    reinterpret_cast<ushort8*>(ebf + (size_t)b * DD)[l] = h;
}

// ---------------- kernel 2a: normalize weights -> bf16 (PRE path) ----------------
__global__ void wnorm_bf16_kernel(const float* __restrict__ w, unsigned short* __restrict__ wbf) {
    const int row = blockIdx.x * 4 + (threadIdx.x >> 6);   // 12500 blocks * 4 waves
    const int l = threadIdx.x & 63;
    const float4* r = reinterpret_cast<const float4*>(w + (size_t)row * DD);
    float4 v0 = r[l * 2 + 0];
    float4 v1 = r[l * 2 + 1];
    float s = v0.x*v0.x + v0.y*v0.y + v0.z*v0.z + v0.w*v0.w
            + v1.x*v1.x + v1.y*v1.y + v1.z*v1.z + v1.w*v1.w;
    #pragma unroll
    for (int m = 1; m < 64; m <<= 1) s += __shfl_xor(s, m);
    float inv = 1.0f / fmaxf(sqrtf(s), 1e-12f);
    ushort8 h;
    h[0]=f2bf(v0.x*inv); h[1]=f2bf(v0.y*inv); h[2]=f2bf(v0.z*inv); h[3]=f2bf(v0.w*inv);
    h[4]=f2bf(v1.x*inv); h[5]=f2bf(v1.y*inv); h[6]=f2bf(v1.z*inv); h[7]=f2bf(v1.w*inv);
    reinterpret_cast<ushort8*>(wbf + (size_t)row * DD)[l] = h;
}

// ---------------- kernel 2b: weight inverse norms (fallback path) ----------------
__global__ void wnorm_kernel(const float* __restrict__ w, float* __restrict__ invn) {
    const int row = blockIdx.x * 4 + (threadIdx.x >> 6);
    const int l = threadIdx.x & 63;
    const float4* r = reinterpret_cast<const float4*>(w + (size_t)row * DD);
    float4 v0 = r[l * 2 + 0];
    float4 v1 = r[l * 2 + 1];
    float s = v0.x*v0.x + v0.y*v0.y + v0.z*v0.z + v0.w*v0.w
            + v1.x*v1.x + v1.y*v1.y + v1.z*v1.z + v1.w*v1.w;
    #pragma unroll
    for (int m = 1; m < 64; m <<= 1) s += __shfl_xor(s, m);
    if (l == 0) invn[row] = 1.0f / fmaxf(sqrtf(s), 1e-12f);
}

// ---------------- kernel 3 (PRE): 256x256x64 8-phase GEMM + arcface + partial lse ----
// 8 waves (2M x 4N); per-wave 128x64 output (8m x 4n frags of 16x16).
// LDS 128 KB: buf b at b*65536: A [256][64]bf16 at +0 (halves 16KB), B at +32768.
// Per K-tile, 4 phases; quadrant order q0=(mlo,nlo) q1=(mhi,nlo) q2=(mlo,nhi) q3=(mhi,nhi).
// LDS A-regions of a tile retire after q1, B-regions after q2.
// Stage schedule during tile t: q0->T(t+1).Blo, q1->T(t+1).Bhi, q2->T(t+2).Alo, q3->T(t+2).Ahi.
// One counted vmcnt per K-tile boundary: vmcnt(4) (2 half-tiles in flight), never 0 mid-loop.
__global__ __launch_bounds__(512, 2) void arc_gemm8_kernel(
        const unsigned short* __restrict__ ebf,
        const unsigned short* __restrict__ wbf,
        const int* __restrict__ labels,
        float* __restrict__ part_m,
        float* __restrict__ part_s,
        float* __restrict__ lab_logit)
{
    __shared__ __align__(16) char lds[131072];

    const int t   = threadIdx.x;       // 0..511
    const int wid = t >> 6;
    const int wm  = wid >> 2;          // 0..1
    const int wn  = wid & 3;           // 0..3
    const int l   = t & 63;
    const int r16 = l & 15;
    const int kg  = l >> 4;

    // XCD-bijective swizzle: 784 = 8*98, m-tile fastest within an XCD chunk
    const int bid  = blockIdx.x;
    const int bidp = (bid & 7) * (NBLK8 / 8) + (bid >> 3);
    const int mt = bidp & 3;
    const int nt = bidp >> 2;          // 0..195
    const int m0 = mt * 256;
    const int c0 = nt * 256;

    // ---- staging helpers (global_load_lds w/ pre-swizzled source) ----
    auto stage_ahalf = [&](int kt, int ha, int ldsbase) {
        #pragma unroll
        for (int r = 0; r < 2; ++r) {
            int flat = (r * 512 + t) * 16;
            int row  = flat >> 7;            // 0..127
            int colb = flat & 127;
            int scol = colb ^ ((row & 7) << 4);
            const char* src = reinterpret_cast<const char*>(ebf)
                            + (size_t)(m0 + ha * 128 + row) * (DD * 2) + kt * 128 + scol;
            __builtin_amdgcn_global_load_lds(
                (const __attribute__((address_space(1))) void*)src,
                (__attribute__((address_space(3))) void*)(&lds[ldsbase + ha * 16384 + flat]),
                16, 0, 0);
        }
    };
    auto stage_bhalf = [&](int kt, int hb, int ldsbase) {
        #pragma unroll
        for (int r = 0; r < 2; ++r) {
            int flat = (r * 512 + t) * 16;
            int row  = flat >> 7;
            int colb = flat & 127;
            int scol = colb ^ ((row & 7) << 4);
            int cls  = c0 + hb * 128 + row;
            if (cls > CC - 1) cls = CC - 1;      // clamp; masked in epilogue
            const char* src = reinterpret_cast<const char*>(wbf)
                            + (size_t)cls * (DD * 2) + kt * 128 + scol;
            __builtin_amdgcn_global_load_lds(
                (const __attribute__((address_space(1))) void*)src,
                (__attribute__((address_space(3))) void*)(&lds[ldsbase + 32768 + hb * 16384 + flat]),
                16, 0, 0);
        }
    };

    const int arow_off = wm * 16384;                 // this wave's A half
    const int brow_off = 32768 + (wn >> 1) * 16384;  // this wave's B half
    const int bcol_loc = (wn & 1) * 64;

    f32x4 acc[8][4];
    #pragma unroll
    for (int m = 0; m < 8; ++m)
        #pragma unroll
        for (int n = 0; n < 4; ++n)
            acc[m][n] = (f32x4){0.f, 0.f, 0.f, 0.f};

    short8 Af[8][2];
    short8 Bf[4][2];

    // ---- prologue: T0 all 4 halves + T1.Alo/Ahi; vmcnt(4) leaves T1.A in flight ----
    stage_ahalf(0, 0, 0); stage_ahalf(0, 1, 0);
    stage_bhalf(0, 0, 0); stage_bhalf(0, 1, 0);
    stage_ahalf(1, 0, 65536); stage_ahalf(1, 1, 65536);
    asm volatile("s_waitcnt vmcnt(4)" ::: "memory");
    __builtin_amdgcn_s_barrier();

    for (int kt = 0; kt < 8; ++kt) {
        const int buf  = (kt & 1) * 65536;
        const int nbuf = buf ^ 65536;

        // ===== phase q0: read Af[0..3], Bf[0..1]; stage T(t+1).Blo =====
        #pragma unroll
        for (int fm = 0; fm < 4; ++fm)
            #pragma unroll
            for (int kk = 0; kk < 2; ++kk) {
                int row = fm * 16 + r16;
                int kb  = (kk * 64 + kg * 16) ^ ((row & 7) << 4);
                Af[fm][kk] = *reinterpret_cast<const short8*>(&lds[buf + arow_off + row * 128 + kb]);
            }
        #pragma unroll
        for (int fn = 0; fn < 2; ++fn)
            #pragma unroll
            for (int kk = 0; kk < 2; ++kk) {
                int row = bcol_loc + fn * 16 + r16;
                int kb  = (kk * 64 + kg * 16) ^ ((row & 7) << 4);
                Bf[fn][kk] = *reinterpret_cast<const short8*>(&lds[buf + brow_off + row * 128 + kb]);
            }
        if (kt + 1 < 8) stage_bhalf(kt + 1, 0, nbuf);
        __builtin_amdgcn_s_barrier();
        __builtin_amdgcn_s_setprio(1);
        #pragma unroll
        for (int fm = 0; fm < 4; ++fm)
            #pragma unroll
            for (int fn = 0; fn < 2; ++fn)
                #pragma unroll
                for (int kk = 0; kk < 2; ++kk)
                    acc[fm][fn] = __builtin_amdgcn_mfma_f32_16x16x32_bf16(Af[fm][kk], Bf[fn][kk], acc[fm][fn], 0, 0, 0);
        __builtin_amdgcn_s_setprio(0);
        __builtin_amdgcn_s_barrier();

        // ===== phase q1: read Af[4..7]; stage T(t+1).Bhi =====
        #pragma unroll
        for (int fm = 4; fm < 8; ++fm)
            #pragma unroll
            for (int kk = 0; kk < 2; ++kk) {
                int row = fm * 16 + r16;
                int kb  = (kk * 64 + kg * 16) ^ ((row & 7) << 4);
                Af[fm][kk] = *reinterpret_cast<const short8*>(&lds[buf + arow_off + row * 128 + kb]);
            }
        if (kt + 1 < 8) stage_bhalf(kt + 1, 1, nbuf);
        __builtin_amdgcn_s_barrier();
        __builtin_amdgcn_s_setprio(1);
        #pragma unroll
        for (int fm = 4; fm < 8; ++fm)
            #pragma unroll
            for (int fn = 0; fn < 2; ++fn)
                #pragma unroll
                for (int kk = 0; kk < 2; ++kk)
                    acc[fm][fn] = __builtin_amdgcn_mfma_f32_16x16x32_bf16(Af[fm][kk], Bf[fn][kk], acc[fm][fn], 0, 0, 0);
        __builtin_amdgcn_s_setprio(0);
        __builtin_amdgcn_s_barrier();

        // ===== phase q2: read Bf[2..3]; stage T(t+2).Alo (A regions of buf retired after q1) =====
        #pragma unroll
        for (int fn = 2; fn < 4; ++fn)
            #pragma unroll
            for (int kk = 0; kk < 2; ++kk) {
                int row = bcol_loc + fn * 16 + r16;
                int kb  = (kk * 64 + kg * 16) ^ ((row & 7) << 4);
                Bf[fn][kk] = *reinterpret_cast<const short8*>(&lds[buf + brow_off + row * 128 + kb]);
            }
        if (kt + 2 < 8) stage_ahalf(kt + 2, 0, buf);
        __builtin_amdgcn_s_barrier();
        __builtin_amdgcn_s_setprio(1);
        #pragma unroll
        for (int fm = 0; fm < 4; ++fm)
            #pragma unroll
            for (int fn = 2; fn < 4; ++fn)
                #pragma unroll
                for (int kk = 0; kk < 2; ++kk)
                    acc[fm][fn] = __builtin_amdgcn_mfma_f32_16x16x32_bf16(Af[fm][kk], Bf[fn][kk], acc[fm][fn], 0, 0, 0);
        __builtin_amdgcn_s_setprio(0);
        __builtin_amdgcn_s_barrier();

        // ===== phase q3: no reads; stage T(t+2).Ahi; boundary wait =====
        if (kt + 2 < 8) stage_ahalf(kt + 2, 1, buf + 16384);
        __builtin_amdgcn_s_barrier();
        __builtin_amdgcn_s_setprio(1);
        #pragma unroll
        for (int fm = 4; fm < 8; ++fm)
            #pragma unroll
            for (int fn = 2; fn < 4; ++fn)
                #pragma unroll
                for (int kk = 0; kk < 2; ++kk)
                    acc[fm][fn] = __builtin_amdgcn_mfma_f32_16x16x32_bf16(Af[fm][kk], Bf[fn][kk], acc[fm][fn], 0, 0, 0);
        __builtin_amdgcn_s_setprio(0);
        if (kt < 6) { asm volatile("s_waitcnt vmcnt(4)" ::: "memory"); }
        else        { asm volatile("s_waitcnt vmcnt(0)" ::: "memory"); }
        __builtin_amdgcn_s_barrier();
    }

    // ---- epilogue: logits, per-row max + sum(exp) over this wave's 64 cols ----
    const int rowb = m0 + wm * 128;
    #pragma unroll
    for (int fm = 0; fm < 8; ++fm) {
        #pragma unroll
        for (int j = 0; j < 4; ++j) {
            const int rl   = fm * 16 + kg * 4 + j;
            const int grow = rowb + rl;
            const int lab  = labels[grow];
            float vals[4];
            float vmax = -1e30f;
            #pragma unroll
            for (int fn = 0; fn < 4; ++fn) {
                float cosv = acc[fm][fn][j];
                int col = c0 + wn * 64 + fn * 16 + r16;
                float logit;
                if (col < CC) {
                    logit = SCALE_F * cosv;
                    if (col == lab) {
                        float c2 = fminf(fmaxf(cosv * cosv, 0.f), 1.f);
                        float phi = cosv * COS_M_F - sqrtf(1.f - c2) * SIN_M_F;
                        phi = (cosv > TH_F) ? phi : (cosv - MM_F);
                        logit = SCALE_F * phi;
                        lab_logit[grow] = logit;
                    }
                } else {
                    logit = -1e30f;
                }
                vals[fn] = logit;
                vmax = fmaxf(vmax, logit);
            }
            #pragma unroll
            for (int mk = 1; mk < 16; mk <<= 1) vmax = fmaxf(vmax, __shfl_xor(vmax, mk));
            float s = 0.f;
            #pragma unroll
            for (int fn = 0; fn < 4; ++fn) s += __expf(vals[fn] - vmax);
            #pragma unroll
            for (int mk = 1; mk < 16; mk <<= 1) s += __shfl_xor(s, mk);
            if (r16 == 0) {
                size_t idx = (size_t)grow * PSTRIDE + nt * 4 + wn;
                part_m[idx] = vmax;
                part_s[idx] = s;
            }
        }
    }
}

// ---------------- kernel 3 (fallback): round-2 2-phase 256x64 GEMM ----------------
__global__ __launch_bounds__(256, 2) void arc_gemm_fb_kernel(
        const unsigned short* __restrict__ ebf,
        const float* __restrict__ wgt,
        const float* __restrict__ invw,
        const int* __restrict__ labels,
        float* __restrict__ part_m,
        float* __restrict__ part_s,
        float* __restrict__ lab_logit)
{
    __shared__ __align__(16) char lds[2][40960];
    const int t  = threadIdx.x;
    const int wv = t >> 6;
    const int l  = t & 63;
    const int r16 = l & 15;
    const int kg  = l >> 4;
    const int bid  = blockIdx.x;
    const int bidp = (bid & 7) * (NBLKFB / 8) + (bid >> 3);
    const int mt = bidp & 3;
    const int bn = bidp >> 2;
    const int m0 = mt * 256;
    const int c0 = bn * 64;

    f32x4 acc[4][4];
    #pragma unroll
    for (int m = 0; m < 4; ++m)
        #pragma unroll
        for (int n = 0; n < 4; ++n)
            acc[m][n] = (f32x4){0.f, 0.f, 0.f, 0.f};

    auto stageA = [&](int buf, int kt) {
        #pragma unroll
        for (int i = 0; i < 8; ++i) {
            int flat = (i * 256 + t) * 16;
            int row  = flat >> 7;
            int col  = (flat & 127) ^ ((row & 7) << 4);
            const char* src = reinterpret_cast<const char*>(ebf)
                            + (size_t)(m0 + row) * (DD * 2) + kt * 128 + col;
            __builtin_amdgcn_global_load_lds(
                (const __attribute__((address_space(1))) void*)(src),
                (__attribute__((address_space(3))) void*)(&lds[buf][flat]),
                16, 0, 0);
        }
    };
    auto stageB = [&](int buf, int kt) {
        #pragma unroll
        for (int i = 0; i < 2; ++i) {
            int chunk = i * 256 + t;
            int row   = chunk >> 3;
            int cb    = chunk & 7;
            int cls   = c0 + row;
            ushort8 hv = (ushort8){0,0,0,0,0,0,0,0};
            if (cls < CC) {
                float inv = invw[cls];
                const float4* src = reinterpret_cast<const float4*>(
                    wgt + (size_t)cls * DD + kt * 64 + cb * 8);
                float4 f0 = src[0];
                float4 f1 = src[1];
                hv[0]=f2bf(f0.x*inv); hv[1]=f2bf(f0.y*inv);
                hv[2]=f2bf(f0.z*inv); hv[3]=f2bf(f0.w*inv);
                hv[4]=f2bf(f1.x*inv); hv[5]=f2bf(f1.y*inv);
                hv[6]=f2bf(f1.z*inv); hv[7]=f2bf(f1.w*inv);
            }
            int dst = 32768 + row * 128 + ((cb * 16) ^ ((row & 7) << 4));
            *reinterpret_cast<ushort8*>(&lds[buf][dst]) = hv;
        }
    };
    auto compute = [&](int buf) {
        #pragma unroll
        for (int kk = 0; kk < 2; ++kk) {
            const int kb = kk * 64 + kg * 16;
            short8 a[4], b[4];
            #pragma unroll
            for (int m = 0; m < 4; ++m) {
                int row = wv * 64 + m * 16 + r16;
                a[m] = *reinterpret_cast<const short8*>(&lds[buf][row * 128 + (kb ^ ((row & 7) << 4))]);
            }
            #pragma unroll
            for (int n = 0; n < 4; ++n) {
                int row = n * 16 + r16;
                b[n] = *reinterpret_cast<const short8*>(&lds[buf][32768 + row * 128 + (kb ^ ((row & 7) << 4))]);
            }
            #pragma unroll
            for (int m = 0; m < 4; ++m)
                #pragma unroll
                for (int n = 0; n < 4; ++n)
                    acc[m][n] = __builtin_amdgcn_mfma_f32_16x16x32_bf16(a[m], b[n], acc[m][n], 0, 0, 0);
        }
    };

    stageA(0, 0); stageB(0, 0);
    __syncthreads();
    #pragma unroll
    for (int kt = 0; kt < 7; ++kt) {
        const int cur = kt & 1;
        stageA(cur ^ 1, kt + 1);
        stageB(cur ^ 1, kt + 1);
        compute(cur);
        __syncthreads();
    }
    compute(1);

    #pragma unroll
    for (int m = 0; m < 4; ++m) {
        #pragma unroll
        for (int j = 0; j < 4; ++j) {
            const int row_local = wv * 64 + m * 16 + kg * 4 + j;
            const int lab = labels[m0 + row_local];
            float vals[4];
            float vmax = -1e30f;
            #pragma unroll
            for (int n = 0; n < 4; ++n) {
                float cosv = acc[m][n][j];
                int col = c0 + n * 16 + r16;
                float logit;
                if (col < CC) {
                    logit = SCALE_F * cosv;
                    if (col == lab) {
                        float c2 = fminf(fmaxf(cosv * cosv, 0.f), 1.f);
                        float phi = cosv * COS_M_F - sqrtf(1.f - c2) * SIN_M_F;
                        phi = (cosv > TH_F) ? phi : (cosv - MM_F);
                        logit = SCALE_F * phi;
                        lab_logit[m0 + row_local] = logit;
                    }
                } else {
                    logit = -1e30f;
                }
                vals[n] = logit;
                vmax = fmaxf(vmax, logit);
            }
            #pragma unroll
            for (int mk = 1; mk < 16; mk <<= 1) vmax = fmaxf(vmax, __shfl_xor(vmax, mk));
            float s = 0.f;
            #pragma unroll
            for (int n = 0; n < 4; ++n) s += __expf(vals[n] - vmax);
            #pragma unroll
            for (int mk = 1; mk < 16; mk <<= 1) s += __shfl_xor(s, mk);
            if (r16 == 0) {
                size_t idx = (size_t)(m0 + row_local) * PSTRIDE + bn;
                part_m[idx] = vmax;
                part_s[idx] = s;
            }
        }
    }
}

// ---------------- kernel 4: per-row logsumexp merge -> nll ----------------
__global__ void row_lse_kernel(const float* __restrict__ part_m,
                               const float* __restrict__ part_s,
                               const float* __restrict__ lab_logit,
                               float* __restrict__ nll, int np) {
    const int row = blockIdx.x;
    const int t = threadIdx.x;   // 256
    const float* pm = part_m + (size_t)row * PSTRIDE;
    const float* ps = part_s + (size_t)row * PSTRIDE;
    float M = -1e30f;
    for (int i = t; i < np; i += 256) M = fmaxf(M, pm[i]);
    #pragma unroll
    for (int m = 1; m < 64; m <<= 1) M = fmaxf(M, __shfl_xor(M, m));
    __shared__ float redm[4];
    if ((t & 63) == 0) redm[t >> 6] = M;
    __syncthreads();
    M = fmaxf(fmaxf(redm[0], redm[1]), fmaxf(redm[2], redm[3]));
    float S = 0.f;
    for (int i = t; i < np; i += 256) S += ps[i] * __expf(pm[i] - M);
    #pragma unroll
    for (int m = 1; m < 64; m <<= 1) S += __shfl_xor(S, m);
    __shared__ float reds[4];
    if ((t & 63) == 0) reds[t >> 6] = S;
    __syncthreads();
    if (t == 0) {
        float Sf = reds[0] + reds[1] + reds[2] + reds[3];
        nll[row] = -(lab_logit[row] - M - logf(Sf));
    }
}

// ---------------- kernel 5: mean over 1024 -> scalar ----------------
__global__ void mean_kernel(const float* __restrict__ nll, float* __restrict__ out) {
    const int t = threadIdx.x;  // 1024
    float v = nll[t];
    #pragma unroll
    for (int m = 1; m < 64; m <<= 1) v += __shfl_xor(v, m);
    __shared__ float red[16];
    if ((t & 63) == 0) red[t >> 6] = v;
    __syncthreads();
    if (t == 0) {
        float s = 0.f;
        #pragma unroll
        for (int i = 0; i < 16; ++i) s += red[i];
        out[0] = s * (1.0f / BB);
    }
}

// ---------------- launcher ----------------
extern "C" void kernel_launch(void* const* d_in, const int* in_sizes, int n_in,
                              void* d_out, int out_size, void* d_ws, size_t ws_size,
                              hipStream_t stream) {
    const float* emb    = (const float*)d_in[0];
    const int*   labels = (const int*)d_in[1];
    const float* wgt    = (const float*)d_in[2];
    float* out = (float*)d_out;
    char* ws = (char*)d_ws;

    float* pm     = (float*)(ws + OFF_PM);
    float* ps     = (float*)(ws + OFF_PS);
    float* lablg  = (float*)(ws + OFF_LAB);
    float* nll    = (float*)(ws + OFF_NLL);
    unsigned short* ebf = (unsigned short*)(ws + OFF_E);

    norm_e_kernel<<<BB, 64, 0, stream>>>(emb, ebf);

    int np;
    if (ws_size >= NEED_PRE) {
        unsigned short* wbf = (unsigned short*)(ws + OFF_WBF);
        wnorm_bf16_kernel<<<CC / 4, 256, 0, stream>>>(wgt, wbf);
        arc_gemm8_kernel<<<NBLK8, 512, 0, stream>>>(ebf, wbf, labels, pm, ps, lablg);
        np = PSTRIDE;
    } else {
        float* invw = (float*)(ws + OFF_INV);
        wnorm_kernel<<<CC / 4, 256, 0, stream>>>(wgt, invw);
        arc_gemm_fb_kernel<<<NBLKFB, 256, 0, stream>>>(ebf, wgt, invw, labels, pm, ps, lablg);
        np = NTFB;
    }

    row_lse_kernel<<<BB, 256, 0, stream>>>(pm, ps, lablg, nll, np);
    mean_kernel<<<1, 1024, 0, stream>>>(nll, out);
}

// Round 4
// 102.644 us; speedup vs baseline: 1.8318x; 1.8318x over previous
//
#include <hip/hip_runtime.h>
#include <hip/hip_bf16.h>
#include <cstdint>

// ---------------- problem constants ----------------
#define BB 1024          // batch
#define DD 512           // dim
#define CC 50000         // classes
#define NTN 391          // ceil(50000/128) n-tiles
#define PSTRIDE 782      // partials per row = NTN * 2 col-halves
#define NBLK 3128        // 8 m-tiles * 391 n-tiles (= 8*391, XCD-divisible)
#define SCALE_F 64.0f
#define COS_M_F 0.87758256189037276f
#define SIN_M_F 0.47942553860420301f
#define TH_F   (-0.87758256189037276f)
#define MM_F   0.23971276930210156f

typedef __attribute__((ext_vector_type(8))) short short8;
typedef __attribute__((ext_vector_type(8))) unsigned short ushort8;
typedef __attribute__((ext_vector_type(4))) float f32x4;

__device__ __forceinline__ unsigned short f2bf(float x) {
    union { __hip_bfloat16 h; unsigned short u; } v;
    v.h = __float2bfloat16(x);
    return v.u;
}

// ---------------- ws layout (bytes) ----------------
#define OFF_PS   ((size_t)0)                          // [1024][782] float
#define OFF_LAB  (OFF_PS + (size_t)BB*PSTRIDE*4)      // [1024] float
#define OFF_NLL  (OFF_LAB + 4096)                     // [1024] float
#define OFF_E    (OFF_NLL + 4096)                     // [1024][512] bf16
#define OFF_WBF  (OFF_E + (size_t)BB*DD*2)            // [50000][512] bf16 normalized

// ---------------- kernel 1: normalize embeddings -> bf16 ----------------
__global__ void norm_e_kernel(const float* __restrict__ e, unsigned short* __restrict__ ebf) {
    const int b = blockIdx.x;          // 1024 blocks
    const int l = threadIdx.x;         // 64 threads
    const float4* row = reinterpret_cast<const float4*>(e + (size_t)b * DD);
    float4 v0 = row[l * 2 + 0];
    float4 v1 = row[l * 2 + 1];
    float s = v0.x*v0.x + v0.y*v0.y + v0.z*v0.z + v0.w*v0.w
            + v1.x*v1.x + v1.y*v1.y + v1.z*v1.z + v1.w*v1.w;
    #pragma unroll
    for (int m = 1; m < 64; m <<= 1) s += __shfl_xor(s, m);
    float inv = 1.0f / fmaxf(sqrtf(s), 1e-12f);
    ushort8 h;
    h[0]=f2bf(v0.x*inv); h[1]=f2bf(v0.y*inv); h[2]=f2bf(v0.z*inv); h[3]=f2bf(v0.w*inv);
    h[4]=f2bf(v1.x*inv); h[5]=f2bf(v1.y*inv); h[6]=f2bf(v1.z*inv); h[7]=f2bf(v1.w*inv);
    reinterpret_cast<ushort8*>(ebf + (size_t)b * DD)[l] = h;
}

// ---------------- kernel 2: normalize weights -> bf16 ----------------
__global__ void wnorm_bf16_kernel(const float* __restrict__ w, unsigned short* __restrict__ wbf) {
    const int row = blockIdx.x * 4 + (threadIdx.x >> 6);   // 12500 blocks * 4 waves
    const int l = threadIdx.x & 63;
    const float4* r = reinterpret_cast<const float4*>(w + (size_t)row * DD);
    float4 v0 = r[l * 2 + 0];
    float4 v1 = r[l * 2 + 1];
    float s = v0.x*v0.x + v0.y*v0.y + v0.z*v0.z + v0.w*v0.w
            + v1.x*v1.x + v1.y*v1.y + v1.z*v1.z + v1.w*v1.w;
    #pragma unroll
    for (int m = 1; m < 64; m <<= 1) s += __shfl_xor(s, m);
    float inv = 1.0f / fmaxf(sqrtf(s), 1e-12f);
    ushort8 h;
    h[0]=f2bf(v0.x*inv); h[1]=f2bf(v0.y*inv); h[2]=f2bf(v0.z*inv); h[3]=f2bf(v0.w*inv);
    h[4]=f2bf(v1.x*inv); h[5]=f2bf(v1.y*inv); h[6]=f2bf(v1.z*inv); h[7]=f2bf(v1.w*inv);
    reinterpret_cast<ushort8*>(wbf + (size_t)row * DD)[l] = h;
}

// ---------------- kernel 3: m97-style 128x128x64 GEMM + arcface + fixed-max lse ----
// 4 waves (2M x 2N); per-wave 64x64 output (4m x 4n frags of 16x16).
// Single-buffered LDS 32 KB (A 16KB @0, B 16KB @16384), 2 barriers/K-iter.
// __launch_bounds__(256,3) -> <=168 VGPR -> 3 blocks/CU = 12 waves/CU.
// Epilogue: fixed max 64.0 (logit <= 64 always) -> no max reduction, no part_m.
__global__ __launch_bounds__(256, 3) void arc_gemm_kernel(
        const unsigned short* __restrict__ ebf,  // [1024][512] bf16 normalized
        const unsigned short* __restrict__ wbf,  // [50000][512] bf16 normalized
        const int* __restrict__ labels,          // [1024]
        float* __restrict__ part_s,              // [1024][782]
        float* __restrict__ lab_logit)           // [1024]
{
    __shared__ __align__(16) char lds[32768];

    const int t   = threadIdx.x;
    const int wv  = t >> 6;
    const int wr  = wv >> 1;           // row half 0..1
    const int wc  = wv & 1;            // col half 0..1
    const int l   = t & 63;
    const int r16 = l & 15;
    const int kg  = l >> 4;

    // XCD-bijective swizzle: 3128 = 8*391; m-tile fastest within an XCD chunk
    const int bid  = blockIdx.x;
    const int bidp = (bid & 7) * NTN + (bid >> 3);
    const int mt = bidp & 7;           // m-tile 0..7
    const int bn = bidp >> 3;          // n-tile 0..390
    const int m0 = mt * 128;
    const int c0 = bn * 128;

    f32x4 acc[4][4];
    #pragma unroll
    for (int m = 0; m < 4; ++m)
        #pragma unroll
        for (int n = 0; n < 4; ++n)
            acc[m][n] = (f32x4){0.f, 0.f, 0.f, 0.f};

    for (int kt = 0; kt < 8; ++kt) {
        // ---- stage A tile [128][64] bf16, swizzled src ----
        #pragma unroll
        for (int i = 0; i < 4; ++i) {
            int flat = (i * 256 + t) * 16;
            int row  = flat >> 7;
            int scol = (flat & 127) ^ ((row & 7) << 4);
            const char* src = reinterpret_cast<const char*>(ebf)
                            + (size_t)(m0 + row) * (DD * 2) + kt * 128 + scol;
            __builtin_amdgcn_global_load_lds(
                (const __attribute__((address_space(1))) void*)src,
                (__attribute__((address_space(3))) void*)(&lds[flat]),
                16, 0, 0);
        }
        // ---- stage B tile [128 classes][64] bf16 ----
        #pragma unroll
        for (int i = 0; i < 4; ++i) {
            int flat = (i * 256 + t) * 16;
            int row  = flat >> 7;
            int scol = (flat & 127) ^ ((row & 7) << 4);
            int cls  = c0 + row;
            if (cls > CC - 1) cls = CC - 1;    // clamp; masked in epilogue
            const char* src = reinterpret_cast<const char*>(wbf)
                            + (size_t)cls * (DD * 2) + kt * 128 + scol;
            __builtin_amdgcn_global_load_lds(
                (const __attribute__((address_space(1))) void*)src,
                (__attribute__((address_space(3))) void*)(&lds[16384 + flat]),
                16, 0, 0);
        }
        __syncthreads();
        // ---- MFMA ----
        #pragma unroll
        for (int kk = 0; kk < 2; ++kk) {
            const int kb = kk * 64 + kg * 16;
            short8 a[4], b[4];
            #pragma unroll
            for (int m = 0; m < 4; ++m) {
                int row = wr * 64 + m * 16 + r16;
                a[m] = *reinterpret_cast<const short8*>(&lds[row * 128 + (kb ^ ((row & 7) << 4))]);
            }
            #pragma unroll
            for (int n = 0; n < 4; ++n) {
                int row = wc * 64 + n * 16 + r16;
                b[n] = *reinterpret_cast<const short8*>(&lds[16384 + row * 128 + (kb ^ ((row & 7) << 4))]);
            }
            #pragma unroll
            for (int m = 0; m < 4; ++m)
                #pragma unroll
                for (int n = 0; n < 4; ++n)
                    acc[m][n] = __builtin_amdgcn_mfma_f32_16x16x32_bf16(a[m], b[n], acc[m][n], 0, 0, 0);
        }
        __syncthreads();
    }

    // ---- epilogue: fixed-max partial sum of exp(logit - 64) over this wave's 64 cols ----
    #pragma unroll
    for (int m = 0; m < 4; ++m) {
        #pragma unroll
        for (int j = 0; j < 4; ++j) {
            const int rl   = wr * 64 + m * 16 + kg * 4 + j;
            const int grow = m0 + rl;
            const int lab  = labels[grow];
            float s = 0.f;
            #pragma unroll
            for (int n = 0; n < 4; ++n) {
                float cosv = acc[m][n][j];
                int col = c0 + wc * 64 + n * 16 + r16;
                if (col < CC) {
                    float logit = SCALE_F * cosv;
                    if (col == lab) {
                        float c2 = fminf(fmaxf(cosv * cosv, 0.f), 1.f);
                        float phi = cosv * COS_M_F - sqrtf(1.f - c2) * SIN_M_F;
                        phi = (cosv > TH_F) ? phi : (cosv - MM_F);
                        logit = SCALE_F * phi;
                        lab_logit[grow] = logit;
                    }
                    s += __expf(logit - SCALE_F);   // logit <= 64 always
                }
            }
            #pragma unroll
            for (int mk = 1; mk < 16; mk <<= 1) s += __shfl_xor(s, mk);
            if (r16 == 0) {
                part_s[(size_t)grow * PSTRIDE + bn * 2 + wc] = s;
            }
        }
    }
}

// ---------------- kernel 4: per-row sum -> nll (fixed max = 64) ----------------
__global__ void row_lse_kernel(const float* __restrict__ part_s,
                               const float* __restrict__ lab_logit,
                               float* __restrict__ nll) {
    const int row = blockIdx.x;
    const int t = threadIdx.x;   // 256
    const float* ps = part_s + (size_t)row * PSTRIDE;
    float S = 0.f;
    for (int i = t; i < PSTRIDE; i += 256) S += ps[i];
    #pragma unroll
    for (int m = 1; m < 64; m <<= 1) S += __shfl_xor(S, m);
    __shared__ float reds[4];
    if ((t & 63) == 0) reds[t >> 6] = S;
    __syncthreads();
    if (t == 0) {
        float Sf = reds[0] + reds[1] + reds[2] + reds[3];
        // logsumexp = 64 + log(sum exp(l - 64)); nll = -(lab - lse)
        nll[row] = -(lab_logit[row] - SCALE_F - logf(Sf));
    }
}

// ---------------- kernel 5: mean over 1024 -> scalar ----------------
__global__ void mean_kernel(const float* __restrict__ nll, float* __restrict__ out) {
    const int t = threadIdx.x;  // 1024
    float v = nll[t];
    #pragma unroll
    for (int m = 1; m < 64; m <<= 1) v += __shfl_xor(v, m);
    __shared__ float red[16];
    if ((t & 63) == 0) red[t >> 6] = v;
    __syncthreads();
    if (t == 0) {
        float s = 0.f;
        #pragma unroll
        for (int i = 0; i < 16; ++i) s += red[i];
        out[0] = s * (1.0f / BB);
    }
}

// ---------------- launcher ----------------
extern "C" void kernel_launch(void* const* d_in, const int* in_sizes, int n_in,
                              void* d_out, int out_size, void* d_ws, size_t ws_size,
                              hipStream_t stream) {
    const float* emb    = (const float*)d_in[0];
    const int*   labels = (const int*)d_in[1];
    const float* wgt    = (const float*)d_in[2];
    float* out = (float*)d_out;
    char* ws = (char*)d_ws;

    float* ps     = (float*)(ws + OFF_PS);
    float* lablg  = (float*)(ws + OFF_LAB);
    float* nll    = (float*)(ws + OFF_NLL);
    unsigned short* ebf = (unsigned short*)(ws + OFF_E);
    unsigned short* wbf = (unsigned short*)(ws + OFF_WBF);

    norm_e_kernel<<<BB, 64, 0, stream>>>(emb, ebf);
    wnorm_bf16_kernel<<<CC / 4, 256, 0, stream>>>(wgt, wbf);
    arc_gemm_kernel<<<NBLK, 256, 0, stream>>>(ebf, wbf, labels, ps, lablg);
    row_lse_kernel<<<BB, 256, 0, stream>>>(ps, lablg, nll);
    mean_kernel<<<1, 1024, 0, stream>>>(nll, out);
}